// Round 11
// baseline (223.365 us; speedup 1.0000x reference)
//
#include <hip/hip_runtime.h>
#include <hip/hip_bf16.h>

typedef __attribute__((ext_vector_type(8))) short bf16x8;
typedef __attribute__((ext_vector_type(4))) float f32x4;
typedef __attribute__((ext_vector_type(4))) unsigned int u32x4;

#define B_  512
#define N_  256
#define SD_ 1024
#define HD_ 512
#define AD_ 256

__device__ __forceinline__ unsigned short f2bf(float f) {
    unsigned int u = __float_as_uint(f);
    unsigned int r = (u + 0x7FFFu + ((u >> 16) & 1u)) >> 16;
    return (unsigned short)r;
}

// hardware packed f32->bf16 (RNE), 2 elems/instr
__device__ __forceinline__ unsigned int cvtpk(float lo, float hi) {
    unsigned int r;
    asm("v_cvt_pk_bf16_f32 %0, %1, %2" : "=v"(r) : "v"(lo), "v"(hi));
    return r;
}

// ---------------------------------------------------------------------------
// K0: pack Wh (AD x HD, f32, row-major) into bf16 B-fragment layout for
// mfma_f32_16x16x32_bf16. Fragment (ct, ks): 64 lanes x 8 bf16 contiguous.
__global__ void k0_pack(const float* __restrict__ Wh, unsigned short* __restrict__ whp) {
    int g = blockIdx.x * 256 + threadIdx.x;
    int ct  = g >> 10;
    int rem = g & 1023;
    int ks  = rem >> 6;
    int l   = rem & 63;
    int a   = ct * 16 + (l & 15);
    int kb  = ks * 32 + (l >> 4) * 8;
    const float* src = Wh + (size_t)a * HD_ + kb;
    float4 v0 = *(const float4*)(src);
    float4 v1 = *(const float4*)(src + 4);
    bf16x8 o;
    o[0] = (short)f2bf(v0.x); o[1] = (short)f2bf(v0.y);
    o[2] = (short)f2bf(v0.z); o[3] = (short)f2bf(v0.w);
    o[4] = (short)f2bf(v1.x); o[5] = (short)f2bf(v1.y);
    o[6] = (short)f2bf(v1.z); o[7] = (short)f2bf(v1.w);
    ((bf16x8*)whp)[g] = o;
}

// ---------------------------------------------------------------------------
// K1: 2 b's per block, 512 threads. sp = state@Ws^T + bs (coalesced Ws reads),
// sn = max(||sp||,eps).
__global__ __launch_bounds__(512) void k1_proj(
    const float* __restrict__ state, const float* __restrict__ Ws,
    const float* __restrict__ bs,
    float* __restrict__ sn, float* __restrict__ spv)
{
    __shared__ float st[2][SD_];
    __shared__ float spl[2][AD_];
    __shared__ float red[2][AD_];
    int tid = threadIdx.x, lane = tid & 63, w = tid >> 6;
    int b0 = blockIdx.x * 2;
    ((float4*)st)[tid] = ((const float4*)(state + (size_t)b0 * SD_))[tid];
    __syncthreads();
    float4 s0[4], s1[4];
    #pragma unroll
    for (int seg = 0; seg < 4; ++seg) {
        s0[seg] = *(const float4*)&st[0][seg * 256 + lane * 4];
        s1[seg] = *(const float4*)&st[1][seg * 256 + lane * 4];
    }
    #pragma unroll 2
    for (int i = 0; i < 32; ++i) {
        int a = w * 32 + i;
        const float4* wr = (const float4*)(Ws + (size_t)a * SD_);
        float p0 = 0.f, p1 = 0.f;
        #pragma unroll
        for (int seg = 0; seg < 4; ++seg) {
            float4 wv = wr[seg * 64 + lane];
            p0 += wv.x * s0[seg].x + wv.y * s0[seg].y + wv.z * s0[seg].z + wv.w * s0[seg].w;
            p1 += wv.x * s1[seg].x + wv.y * s1[seg].y + wv.z * s1[seg].z + wv.w * s1[seg].w;
        }
        #pragma unroll
        for (int d = 1; d < 64; d <<= 1) { p0 += __shfl_xor(p0, d); p1 += __shfl_xor(p1, d); }
        if (lane == 0) {
            float bsa = bs[a];
            spl[0][a] = p0 + bsa;
            spl[1][a] = p1 + bsa;
        }
    }
    __syncthreads();
    int tb = tid >> 8, t = tid & 255;
    float sv = spl[tb][t];
    spv[(size_t)(b0 + tb) * AD_ + t] = sv;
    red[tb][t] = sv * sv;
    __syncthreads();
    for (int s = 128; s > 0; s >>= 1) { if (t < s) red[tb][t] += red[tb][t + s]; __syncthreads(); }
    if (t == 0) sn[b0 + tb] = fmaxf(sqrtf(red[tb][0]), 1e-8f);
}

// ---------------------------------------------------------------------------
// K2a: streaming scores. 2048 blocks x 256 threads (4 waves). Block = 64 rows
// of one b; wave w = cols [w*64, w*64+64). NO LDS / NO BARRIERS in the k-sweep:
// A-fragments loaded directly from global (f32, 16 rows x 128B per kidx; the
// 4 waves share lines via L1), converted in-register with v_cvt_pk_bf16_f32;
// B-fragments direct from L2-resident whp. Waves free-run -> HBM queue never
// drains (the R7-R10 stage/barrier structures all pinned at 21% HBM).
__global__ __launch_bounds__(256, 3) void k2_scores(
    const float* __restrict__ hints, const unsigned short* __restrict__ whp,
    const float* __restrict__ spv, const float* __restrict__ sn,
    const float* __restrict__ bh, float* __restrict__ scores)
{
    __shared__ float norm2p[4][64];
    __shared__ float nump[4][64];
    int tid = threadIdx.x, lane = tid & 63, w = tid >> 6;
    int blk = blockIdx.x;
    int b = blk >> 2, m0 = (blk & 3) * 64;
    const float* hb = hints + ((size_t)b * N_ + m0) * HD_;
    int cl = lane & 15, q = lane >> 4;

    float bhv[4], spc[4];
    #pragma unroll
    for (int ctl = 0; ctl < 4; ++ctl) {
        int col = w * 64 + ctl * 16 + cl;
        bhv[ctl] = bh[col];
        spc[ctl] = spv[(size_t)b * AD_ + col];
    }
    float snb = sn[b];

    f32x4 acc[4][4];   // [mf][ctl]
    #pragma unroll
    for (int mf = 0; mf < 4; ++mf)
        #pragma unroll
        for (int ctl = 0; ctl < 4; ++ctl) acc[mf][ctl] = (f32x4){0.f, 0.f, 0.f, 0.f};

    const float* abase = hb + (size_t)cl * HD_ + q * 8;
    const bf16x8* wp = (const bf16x8*)whp + (size_t)(w * 4) * 16 * 64 + lane;

    #pragma unroll
    for (int kidx = 0; kidx < 16; ++kidx) {
        bf16x8 bfr[4];
        #pragma unroll
        for (int ctl = 0; ctl < 4; ++ctl)
            bfr[ctl] = wp[(ctl * 16 + kidx) * 64];
        #pragma unroll
        for (int mf = 0; mf < 4; ++mf) {
            const float* ap = abase + (size_t)(mf * 16) * HD_ + kidx * 32;
            float4 a0 = *(const float4*)ap;
            float4 a1 = *(const float4*)(ap + 4);
            u32x4 t;
            t[0] = cvtpk(a0.x, a0.y);
            t[1] = cvtpk(a0.z, a0.w);
            t[2] = cvtpk(a1.x, a1.y);
            t[3] = cvtpk(a1.z, a1.w);
            bf16x8 afr = __builtin_bit_cast(bf16x8, t);
            #pragma unroll
            for (int ctl = 0; ctl < 4; ++ctl)
                acc[mf][ctl] = __builtin_amdgcn_mfma_f32_16x16x32_bf16(afr, bfr[ctl], acc[mf][ctl], 0, 0, 0);
        }
    }

    // reduce: C layout col = ct*16+cl, row = mf*16 + q*4 + r
    #pragma unroll
    for (int mf = 0; mf < 4; ++mf) {
        #pragma unroll
        for (int r = 0; r < 4; ++r) {
            float vv = 0.f, uu = 0.f;
            #pragma unroll
            for (int ctl = 0; ctl < 4; ++ctl) {
                float h = acc[mf][ctl][r] + bhv[ctl];
                vv += h * h;
                uu += spc[ctl] * h;
            }
            vv += __shfl_xor(vv, 1); uu += __shfl_xor(uu, 1);
            vv += __shfl_xor(vv, 2); uu += __shfl_xor(uu, 2);
            vv += __shfl_xor(vv, 4); uu += __shfl_xor(uu, 4);
            vv += __shfl_xor(vv, 8); uu += __shfl_xor(uu, 8);
            if (cl == 0) {
                int row = mf * 16 + q * 4 + r;
                norm2p[w][row] = vv;
                nump[w][row]   = uu;
            }
        }
    }
    __syncthreads();
    if (tid < 64) {
        float n2 = norm2p[0][tid] + norm2p[1][tid] + norm2p[2][tid] + norm2p[3][tid];
        float nm = nump[0][tid] + nump[1][tid] + nump[2][tid] + nump[3][tid];
        float hn = fmaxf(sqrtf(n2), 1e-8f);
        scores[(size_t)b * N_ + m0 + tid] = nm / (snb * hn);
    }
}

// ---------------------------------------------------------------------------
// K2b: per b: softmax over 256 scores, then weighted sum over hints (L3-warm).
__global__ __launch_bounds__(512) void k2b_out(
    const float* __restrict__ hints, const float* __restrict__ scores,
    float* __restrict__ out)
{
    __shared__ float sc[N_];
    __shared__ float red[N_];
    __shared__ float wsm[N_];
    __shared__ float scratch[2048];
    int tid = threadIdx.x;
    int b = blockIdx.x;
    const float* hb = hints + (size_t)b * N_ * HD_;
    if (tid < 256) sc[tid] = scores[(size_t)b * N_ + tid];
    __syncthreads();
    if (tid < 256) red[tid] = sc[tid];
    __syncthreads();
    for (int s = 128; s > 0; s >>= 1) { if (tid < s) red[tid] = fmaxf(red[tid], red[tid + s]); __syncthreads(); }
    float mx = red[0];
    __syncthreads();
    if (tid < 256) { float e = __expf(sc[tid] - mx); sc[tid] = e; red[tid] = e; }
    __syncthreads();
    for (int s = 128; s > 0; s >>= 1) { if (tid < s) red[tid] += red[tid + s]; __syncthreads(); }
    float inv = 1.f / red[0];
    __syncthreads();
    if (tid < 256) wsm[tid] = sc[tid] * inv;
    __syncthreads();

    int hg = tid & 127, ng = tid >> 7;
    const float* hbe = hb + (size_t)(ng * 64) * HD_ + hg * 4;
    float ax = 0.f, ay = 0.f, az = 0.f, aw = 0.f;
    #pragma unroll 8
    for (int n = 0; n < 64; ++n) {
        float4 hv = *(const float4*)(hbe + (size_t)n * HD_);
        float wn = wsm[ng * 64 + n];
        ax += wn * hv.x; ay += wn * hv.y; az += wn * hv.z; aw += wn * hv.w;
    }
    *(float4*)(scratch + ng * 512 + hg * 4) = (float4){ax, ay, az, aw};
    __syncthreads();
    out[(size_t)b * HD_ + tid] =
        scratch[tid] + scratch[512 + tid] + scratch[1024 + tid] + scratch[1536 + tid];
}

// ---------------------------------------------------------------------------
extern "C" void kernel_launch(void* const* d_in, const int* in_sizes, int n_in,
                              void* d_out, int out_size, void* d_ws, size_t ws_size,
                              hipStream_t stream) {
    const float* state = (const float*)d_in[0];
    const float* hints = (const float*)d_in[1];
    const float* Ws    = (const float*)d_in[2];
    const float* bs    = (const float*)d_in[3];
    const float* Wh    = (const float*)d_in[4];
    const float* bh    = (const float*)d_in[5];
    float* out = (float*)d_out;

    float* sn = (float*)d_ws;                              // B
    float* spv = sn + B_;                                  // B*AD
    unsigned short* whp = (unsigned short*)(spv + (size_t)B_ * AD_);  // AD*HD bf16
    float* scores = (float*)(whp + (size_t)AD_ * HD_);     // B*N

    k0_pack<<<64, 256, 0, stream>>>(Wh, whp);
    k1_proj<<<B_ / 2, 512, 0, stream>>>(state, Ws, bs, sn, spv);
    k2_scores<<<B_ * 4, 256, 0, stream>>>(hints, whp, spv, sn, bh, scores);
    k2b_out<<<B_, 512, 0, stream>>>(hints, scores, out);
}

// Round 12
// 171.981 us; speedup vs baseline: 1.2988x; 1.2988x over previous
//
#include <hip/hip_runtime.h>
#include <hip/hip_bf16.h>

typedef __attribute__((ext_vector_type(8))) short bf16x8;
typedef __attribute__((ext_vector_type(4))) float f32x4;
typedef __attribute__((ext_vector_type(4))) unsigned int u32x4;

#define B_  512
#define N_  256
#define SD_ 1024
#define HD_ 512
#define AD_ 256

__device__ __forceinline__ unsigned short f2bf(float f) {
    unsigned int u = __float_as_uint(f);
    unsigned int r = (u + 0x7FFFu + ((u >> 16) & 1u)) >> 16;
    return (unsigned short)r;
}

// hardware packed f32->bf16 (RNE), 2 elems/instr
__device__ __forceinline__ unsigned int cvtpk(float lo, float hi) {
    unsigned int r;
    asm("v_cvt_pk_bf16_f32 %0, %1, %2" : "=v"(r) : "v"(lo), "v"(hi));
    return r;
}

// async global->LDS, 16B per lane (HW writes wave-uniform base + lane*16)
__device__ __forceinline__ void gload16(const float* g, char* l) {
    __builtin_amdgcn_global_load_lds(
        (const __attribute__((address_space(1))) unsigned int*)g,
        (__attribute__((address_space(3))) unsigned int*)l, 16, 0, 0);
}

// ---------------------------------------------------------------------------
// K0: pack Wh (AD x HD, f32) into bf16 B-fragment layout for 16x16x32 MFMA.
__global__ void k0_pack(const float* __restrict__ Wh, unsigned short* __restrict__ whp) {
    int g = blockIdx.x * 256 + threadIdx.x;
    int ct  = g >> 10;
    int rem = g & 1023;
    int ks  = rem >> 6;
    int l   = rem & 63;
    int a   = ct * 16 + (l & 15);
    int kb  = ks * 32 + (l >> 4) * 8;
    const float* src = Wh + (size_t)a * HD_ + kb;
    float4 v0 = *(const float4*)(src);
    float4 v1 = *(const float4*)(src + 4);
    bf16x8 o;
    o[0] = (short)f2bf(v0.x); o[1] = (short)f2bf(v0.y);
    o[2] = (short)f2bf(v0.z); o[3] = (short)f2bf(v0.w);
    o[4] = (short)f2bf(v1.x); o[5] = (short)f2bf(v1.y);
    o[6] = (short)f2bf(v1.z); o[7] = (short)f2bf(v1.w);
    ((bf16x8*)whp)[g] = o;
}

// ---------------------------------------------------------------------------
// K1: 2 b's per block, 512 threads. sp = state@Ws^T + bs; sn = max(||sp||,eps).
__global__ __launch_bounds__(512) void k1_proj(
    const float* __restrict__ state, const float* __restrict__ Ws,
    const float* __restrict__ bs,
    float* __restrict__ sn, float* __restrict__ spv)
{
    __shared__ float st[2][SD_];
    __shared__ float spl[2][AD_];
    __shared__ float red[2][AD_];
    int tid = threadIdx.x, lane = tid & 63, w = tid >> 6;
    int b0 = blockIdx.x * 2;
    ((float4*)st)[tid] = ((const float4*)(state + (size_t)b0 * SD_))[tid];
    __syncthreads();
    float4 s0[4], s1[4];
    #pragma unroll
    for (int seg = 0; seg < 4; ++seg) {
        s0[seg] = *(const float4*)&st[0][seg * 256 + lane * 4];
        s1[seg] = *(const float4*)&st[1][seg * 256 + lane * 4];
    }
    #pragma unroll 2
    for (int i = 0; i < 32; ++i) {
        int a = w * 32 + i;
        const float4* wr = (const float4*)(Ws + (size_t)a * SD_);
        float p0 = 0.f, p1 = 0.f;
        #pragma unroll
        for (int seg = 0; seg < 4; ++seg) {
            float4 wv = wr[seg * 64 + lane];
            p0 += wv.x * s0[seg].x + wv.y * s0[seg].y + wv.z * s0[seg].z + wv.w * s0[seg].w;
            p1 += wv.x * s1[seg].x + wv.y * s1[seg].y + wv.z * s1[seg].z + wv.w * s1[seg].w;
        }
        #pragma unroll
        for (int d = 1; d < 64; d <<= 1) { p0 += __shfl_xor(p0, d); p1 += __shfl_xor(p1, d); }
        if (lane == 0) {
            float bsa = bs[a];
            spl[0][a] = p0 + bsa;
            spl[1][a] = p1 + bsa;
        }
    }
    __syncthreads();
    int tb = tid >> 8, t = tid & 255;
    float sv = spl[tb][t];
    spv[(size_t)(b0 + tb) * AD_ + t] = sv;
    red[tb][t] = sv * sv;
    __syncthreads();
    for (int s = 128; s > 0; s >>= 1) { if (t < s) red[tb][t] += red[tb][t + s]; __syncthreads(); }
    if (t == 0) sn[b0 + tb] = fmaxf(sqrtf(red[tb][0]), 1e-8f);
}

// ---------------------------------------------------------------------------
// K2a: scores via global_load_lds staging (Common-mistake #1 fix: staging is
// 4 instrs/thread/chunk instead of ~24 reg/VALU ops, so the 32KB burst hits
// the memory queue instantly). LDS holds raw f32, linear layout (HW reqt);
// bank-swizzle done by pre-swizzling the per-lane GLOBAL source (m173):
// logical granule L (32B) of row r lives at phys granule L^(r&15).
// Fragments: 2x ds_read_b128 + 4x v_cvt_pk_bf16_f32. Wave w: row-half
// (w&1)*32, col-group (w>>1)*64. Each LDS byte read by 4 waves (not 8).
__global__ __launch_bounds__(512, 2) void k2_scores(
    const float* __restrict__ hints, const unsigned short* __restrict__ whp,
    const float* __restrict__ spv, const float* __restrict__ sn,
    const float* __restrict__ bh, float* __restrict__ scores)
{
    __shared__ __align__(16) char smem[69632];
    char* bufA = smem;                       // 32KB: [64 rows][512B], swizzled
    char* bufB = smem + 32768;               // 32KB
    float* sp_lds  = (float*)(smem + 65536); // 1KB
    float* bh_lds  = (float*)(smem + 66560); // 1KB
    float* norm2p  = (float*)(smem + 67584); // [4][64] = 1KB
    float* nump    = (float*)(smem + 68608); // 1KB

    int tid = threadIdx.x, lane = tid & 63, w = tid >> 6;
    int b = blockIdx.x;
    const float* hb = hints + (size_t)b * N_ * HD_;
    if (tid < 64) ((float4*)sp_lds)[tid] = ((const float4*)(spv + (size_t)b * AD_))[tid];
    else if (tid < 128) ((float4*)bh_lds)[tid - 64] = ((const float4*)bh)[tid - 64];
    float snb = sn[b];
    int cl = lane & 15, q = lane >> 4;
    int rh = (w & 1) * 32;        // row half
    int g  = w >> 1;              // col group (4 ct)
    // staging decomposition of tid: 4 segs x (row = s*16 + tid>>5, 16B piece)
    int srow = tid >> 5;          // 0..15
    int sgp  = (tid & 31) >> 1;   // phys granule 0..15
    int shalf = tid & 1;
    __syncthreads();
    float bhv[4], spc[4];
    #pragma unroll
    for (int ci = 0; ci < 4; ++ci) {
        int col = (g * 4 + ci) * 16 + cl;
        bhv[ci] = bh_lds[col];
        spc[ci] = sp_lds[col];
    }

    // STAGE chunk c (= mc*4+kc: rows mc*64..+64, K floats kc*128..+128)
#define STAGE(c, buf) do {                                                     \
    int mcs = (c) >> 2, kcs = (c) & 3;                                         \
    _Pragma("unroll")                                                          \
    for (int s = 0; s < 4; ++s) {                                              \
        int row = s * 16 + srow;                                               \
        const float* gsrc = hb + (size_t)(mcs * 64 + row) * HD_ + kcs * 128    \
                            + ((sgp ^ (row & 15)) << 3) + shalf * 4;           \
        gload16(gsrc, (buf) + s * 8192 + tid * 16);                            \
    }                                                                          \
} while (0)

    STAGE(0, bufA);
    __syncthreads();

    for (int mc = 0; mc < 4; ++mc) {
        f32x4 acc[2][4];
        #pragma unroll
        for (int mf = 0; mf < 2; ++mf)
            #pragma unroll
            for (int ci = 0; ci < 4; ++ci) acc[mf][ci] = (f32x4){0.f, 0.f, 0.f, 0.f};

        #pragma unroll
        for (int kc = 0; kc < 4; ++kc) {
            int c = mc * 4 + kc;
            if (c + 1 < 16) STAGE(c + 1, (c & 1) ? bufA : bufB);
            const char* bR = (c & 1) ? bufB : bufA;
            #pragma unroll
            for (int kk = 0; kk < 4; ++kk) {
                bf16x8 bfr[4];
                #pragma unroll
                for (int ci = 0; ci < 4; ++ci)
                    bfr[ci] = ((const bf16x8*)whp)[((g * 4 + ci) * 16 + kc * 4 + kk) * 64 + lane];
                #pragma unroll
                for (int mf = 0; mf < 2; ++mf) {
                    int r = rh + mf * 16 + cl;
                    const char* ap = bR + r * 512 + (((kk * 4 + q) ^ cl) << 5);
                    float4 lo = *(const float4*)ap;
                    float4 hi = *(const float4*)(ap + 16);
                    u32x4 t;
                    t[0] = cvtpk(lo.x, lo.y);
                    t[1] = cvtpk(lo.z, lo.w);
                    t[2] = cvtpk(hi.x, hi.y);
                    t[3] = cvtpk(hi.z, hi.w);
                    bf16x8 afr = __builtin_bit_cast(bf16x8, t);
                    #pragma unroll
                    for (int ci = 0; ci < 4; ++ci)
                        acc[mf][ci] = __builtin_amdgcn_mfma_f32_16x16x32_bf16(afr, bfr[ci], acc[mf][ci], 0, 0, 0);
                }
            }
            __syncthreads();
        }

        // norm2 + numerator. C layout: col = ct*16+cl, row = mf16 + q*4 + r
        #pragma unroll
        for (int mf = 0; mf < 2; ++mf) {
            #pragma unroll
            for (int r = 0; r < 4; ++r) {
                float vv = 0.f, uu = 0.f;
                #pragma unroll
                for (int ci = 0; ci < 4; ++ci) {
                    float h = acc[mf][ci][r] + bhv[ci];
                    vv += h * h;
                    uu += spc[ci] * h;
                }
                vv += __shfl_xor(vv, 1); uu += __shfl_xor(uu, 1);
                vv += __shfl_xor(vv, 2); uu += __shfl_xor(uu, 2);
                vv += __shfl_xor(vv, 4); uu += __shfl_xor(uu, 4);
                vv += __shfl_xor(vv, 8); uu += __shfl_xor(uu, 8);
                if (cl == 0) {
                    int row = rh + mf * 16 + q * 4 + r;
                    norm2p[g * 64 + row] = vv;
                    nump[g * 64 + row]   = uu;
                }
            }
        }
        __syncthreads();
        if (tid < 64) {
            float n2 = norm2p[tid] + norm2p[64 + tid] + norm2p[128 + tid] + norm2p[192 + tid];
            float nm = nump[tid] + nump[64 + tid] + nump[128 + tid] + nump[192 + tid];
            float hn = fmaxf(sqrtf(n2), 1e-8f);
            scores[(size_t)b * N_ + mc * 64 + tid] = nm / (snb * hn);
        }
        __syncthreads();
    }
#undef STAGE
}

// ---------------------------------------------------------------------------
// K2b: per b: softmax over 256 scores, then weighted sum over hints (L3-warm).
__global__ __launch_bounds__(512) void k2b_out(
    const float* __restrict__ hints, const float* __restrict__ scores,
    float* __restrict__ out)
{
    __shared__ float sc[N_];
    __shared__ float red[N_];
    __shared__ float wsm[N_];
    __shared__ float scratch[2048];
    int tid = threadIdx.x;
    int b = blockIdx.x;
    const float* hb = hints + (size_t)b * N_ * HD_;
    if (tid < 256) sc[tid] = scores[(size_t)b * N_ + tid];
    __syncthreads();
    if (tid < 256) red[tid] = sc[tid];
    __syncthreads();
    for (int s = 128; s > 0; s >>= 1) { if (tid < s) red[tid] = fmaxf(red[tid], red[tid + s]); __syncthreads(); }
    float mx = red[0];
    __syncthreads();
    if (tid < 256) { float e = __expf(sc[tid] - mx); sc[tid] = e; red[tid] = e; }
    __syncthreads();
    for (int s = 128; s > 0; s >>= 1) { if (tid < s) red[tid] += red[tid + s]; __syncthreads(); }
    float inv = 1.f / red[0];
    __syncthreads();
    if (tid < 256) wsm[tid] = sc[tid] * inv;
    __syncthreads();

    int hg = tid & 127, ng = tid >> 7;
    const float* hbe = hb + (size_t)(ng * 64) * HD_ + hg * 4;
    float ax = 0.f, ay = 0.f, az = 0.f, aw = 0.f;
    #pragma unroll 8
    for (int n = 0; n < 64; ++n) {
        float4 hv = *(const float4*)(hbe + (size_t)n * HD_);
        float wn = wsm[ng * 64 + n];
        ax += wn * hv.x; ay += wn * hv.y; az += wn * hv.z; aw += wn * hv.w;
    }
    *(float4*)(scratch + ng * 512 + hg * 4) = (float4){ax, ay, az, aw};
    __syncthreads();
    out[(size_t)b * HD_ + tid] =
        scratch[tid] + scratch[512 + tid] + scratch[1024 + tid] + scratch[1536 + tid];
}

// ---------------------------------------------------------------------------
extern "C" void kernel_launch(void* const* d_in, const int* in_sizes, int n_in,
                              void* d_out, int out_size, void* d_ws, size_t ws_size,
                              hipStream_t stream) {
    const float* state = (const float*)d_in[0];
    const float* hints = (const float*)d_in[1];
    const float* Ws    = (const float*)d_in[2];
    const float* bs    = (const float*)d_in[3];
    const float* Wh    = (const float*)d_in[4];
    const float* bh    = (const float*)d_in[5];
    float* out = (float*)d_out;

    float* sn = (float*)d_ws;                              // B
    float* spv = sn + B_;                                  // B*AD
    unsigned short* whp = (unsigned short*)(spv + (size_t)B_ * AD_);  // AD*HD bf16
    float* scores = (float*)(whp + (size_t)AD_ * HD_);     // B*N

    k0_pack<<<64, 256, 0, stream>>>(Wh, whp);
    k1_proj<<<B_ / 2, 512, 0, stream>>>(state, Ws, bs, sn, spv);
    k2_scores<<<B_, 512, 0, stream>>>(hints, whp, spv, sn, bh, scores);
    k2b_out<<<B_, 512, 0, stream>>>(hints, scores, out);
}